// Round 9
// baseline (242.821 us; speedup 1.0000x reference)
//
#include <hip/hip_runtime.h>
#include <math.h>

#define NP 1000000
#define NE (2 * NP)
#define P 4096
#define D 64
#define H 4
#define HD 16

#define BCAP 1024   // padded capacity per bin (max count ~620 for uniform 2M/4096)
#define KC 8        // K-splits across blocks for flash

typedef short s4v __attribute__((ext_vector_type(4)));
typedef short s8v __attribute__((ext_vector_type(8)));
typedef float f4v __attribute__((ext_vector_type(4)));

__device__ __forceinline__ float softplus_f(float x) {
    return fmaxf(x, 0.0f) + log1pf(__expf(-fabsf(x)));
}
__device__ __forceinline__ unsigned short f2bf_rne(float f) {
    unsigned int b = __float_as_uint(f);
    b += 0x7fffu + ((b >> 16) & 1u);
    return (unsigned short)(b >> 16);
}

// ---------------- single-pass scatter: event -> both bins' padded regions ----------------
__global__ void __launch_bounds__(512) place_single(
        const int2* __restrict__ pairs2, const float* __restrict__ times,
        const float* __restrict__ mom, const float* __restrict__ pos,
        int* __restrict__ gcount, float4* __restrict__ sfeats) {
    int ev = blockIdx.x * 512 + threadIdx.x;
    if (ev >= NP) return;
    float4 f; f.x = times[ev]; f.y = mom[ev]; f.z = pos[ev]; f.w = 0.0f;
    int2 pq = pairs2[ev];
    int r1 = atomicAdd(&gcount[pq.x], 1);
    if (r1 < BCAP) sfeats[((size_t)pq.x << 10) + r1] = f;
    int r2 = atomicAdd(&gcount[pq.y], 1);
    if (r2 < BCAP) sfeats[((size_t)pq.y << 10) + r2] = f;
}

// ---------------- gather-reduce: 2 waves/bin, lane = 8-entry-slot x 8-dim-group ----------------
#define GBODY(fv)                                                              \
    {                                                                          \
        float u0 = fmaf(fv.x, w0a[0], fmaf(fv.y, w1a[0], fmaf(fv.z, w2a[0], ba[0]))); \
        float u1 = fmaf(fv.x, w0a[1], fmaf(fv.y, w1a[1], fmaf(fv.z, w2a[1], ba[1]))); \
        float u2 = fmaf(fv.x, w0a[2], fmaf(fv.y, w1a[2], fmaf(fv.z, w2a[2], ba[2]))); \
        float u3 = fmaf(fv.x, w0a[3], fmaf(fv.y, w1a[3], fmaf(fv.z, w2a[3], ba[3]))); \
        float u4 = fmaf(fv.x, w0b[0], fmaf(fv.y, w1b[0], fmaf(fv.z, w2b[0], bbv[0]))); \
        float u5 = fmaf(fv.x, w0b[1], fmaf(fv.y, w1b[1], fmaf(fv.z, w2b[1], bbv[1]))); \
        float u6 = fmaf(fv.x, w0b[2], fmaf(fv.y, w1b[2], fmaf(fv.z, w2b[2], bbv[2]))); \
        float u7 = fmaf(fv.x, w0b[3], fmaf(fv.y, w1b[3], fmaf(fv.z, w2b[3], bbv[3]))); \
        racc[0] += __builtin_amdgcn_rcpf(__builtin_amdgcn_exp2f(u0) + 1.0f);   \
        racc[1] += __builtin_amdgcn_rcpf(__builtin_amdgcn_exp2f(u1) + 1.0f);   \
        racc[2] += __builtin_amdgcn_rcpf(__builtin_amdgcn_exp2f(u2) + 1.0f);   \
        racc[3] += __builtin_amdgcn_rcpf(__builtin_amdgcn_exp2f(u3) + 1.0f);   \
        racc[4] += __builtin_amdgcn_rcpf(__builtin_amdgcn_exp2f(u4) + 1.0f);   \
        racc[5] += __builtin_amdgcn_rcpf(__builtin_amdgcn_exp2f(u5) + 1.0f);   \
        racc[6] += __builtin_amdgcn_rcpf(__builtin_amdgcn_exp2f(u6) + 1.0f);   \
        racc[7] += __builtin_amdgcn_rcpf(__builtin_amdgcn_exp2f(u7) + 1.0f);   \
    }

__global__ void __launch_bounds__(512) gather_kernel(
        const float4* __restrict__ sfeats, const int* __restrict__ gcount,
        const float* __restrict__ Wenc, const float* __restrict__ benc,
        const float* __restrict__ pemb, float* __restrict__ x) {
    __shared__ float sred[4][16][68];   // [bin-in-block][slot(2wv x 8es)][dim+pad]
    const int tid = threadIdx.x;
    const int wv = tid >> 6, ln = tid & 63;
    const int bi = wv >> 1, hw = wv & 1;
    const int es = ln & 7, dg = ln >> 3;
    const int b = blockIdx.x * 4 + bi;
    const int d0 = dg * 8;
    const float C = 2.8853900817779268f;    // 2*log2(e)
    f4v w0a = *(const f4v*)(Wenc + d0);          f4v w0b = *(const f4v*)(Wenc + d0 + 4);
    f4v w1a = *(const f4v*)(Wenc + D + d0);      f4v w1b = *(const f4v*)(Wenc + D + d0 + 4);
    f4v w2a = *(const f4v*)(Wenc + 2 * D + d0);  f4v w2b = *(const f4v*)(Wenc + 2 * D + d0 + 4);
    f4v ba  = *(const f4v*)(benc + d0);          f4v bbv = *(const f4v*)(benc + d0 + 4);
    w0a *= C; w0b *= C; w1a *= C; w1b *= C; w2a *= C; w2b *= C; ba *= C; bbv *= C;

    const int cnt = min(gcount[b], BCAP);
    const int s0 = b << 10;
    const int half = (cnt + 1) >> 1;
    const int lo = s0 + hw * half;
    const int hi = hw ? (s0 + cnt) : (s0 + half);

    float racc[8];
#pragma unroll
    for (int j = 0; j < 8; ++j) racc[j] = 0.0f;
    int ncnt = 0;
    int base = lo;
    for (; base + 16 <= hi; base += 16) {
        float4 f0 = sfeats[base + es];
        float4 f1 = sfeats[base + 8 + es];
        GBODY(f0);
        GBODY(f1);
        ncnt += 2;
    }
    if (base + 8 <= hi) {
        float4 f0 = sfeats[base + es];
        GBODY(f0);
        ncnt += 1;
        base += 8;
    }
    if (base < hi) {
        const int n = hi - base;
        const bool valid = es < n;
        float4 f = valid ? sfeats[base + es] : make_float4(0.f, 0.f, 0.f, 0.f);
        float save[8];
#pragma unroll
        for (int j = 0; j < 8; ++j) save[j] = racc[j];
        GBODY(f);
        if (!valid) {
#pragma unroll
            for (int j = 0; j < 8; ++j) racc[j] = save[j];
        } else {
            ncnt += 1;
        }
    }
    const float fn = (float)ncnt;
    float* sw = &sred[bi][hw * 8 + es][d0];
#pragma unroll
    for (int j = 0; j < 8; ++j) sw[j] = fmaf(-2.0f, racc[j], fn);
    __syncthreads();
    if (tid < 256) {
        int bin = tid >> 6, dim = tid & 63;
        float s = 0.0f;
#pragma unroll
        for (int e2 = 0; e2 < 16; ++e2) s += sred[bin][e2][dim];
        int gb = blockIdx.x * 4 + bin;
        float c2 = (float)min(gcount[gb], BCAP);
        x[gb * D + dim] = pemb[gb * D + dim] + s / fmaxf(c2, 1.0f);
    }
}

// ---------------- QKV projections -> bf16 Q (scaled by 0.25*log2e), K, V^T ----------------
__global__ void qkv_kernel(const float* __restrict__ x,
                           const float* __restrict__ Wq, const float* __restrict__ bq,
                           const float* __restrict__ Wk, const float* __restrict__ bk,
                           const float* __restrict__ Wv, const float* __restrict__ bv,
                           unsigned short* __restrict__ Qb, unsigned short* __restrict__ Kb,
                           unsigned short* __restrict__ Vb) {
    __shared__ float xs[4][D];
    const int r0 = blockIdx.x * 4;
    const int tid = threadIdx.x;
    xs[tid >> 6][tid & 63] = x[r0 * D + tid];
    __syncthreads();
    const int row = tid >> 6, col = tid & 63;
    float aq = bq[col], ak = bk[col], av = bv[col];
    for (int d = 0; d < D; ++d) {
        float xv = xs[row][d];
        aq = fmaf(xv, Wq[d * D + col], aq);
        ak = fmaf(xv, Wk[d * D + col], ak);
        av = fmaf(xv, Wv[d * D + col], av);
    }
    const int h = col >> 4, hd = col & 15, gr = r0 + row;
    Qb[((h * P + gr) << 4) + hd] = f2bf_rne(aq * 0.3606737602222409f);  // 0.25*log2(e)
    Kb[((h * P + gr) << 4) + hd] = f2bf_rne(ak);
    Vb[(size_t)(h * 16 + hd) * P + gr] = f2bf_rne(av);
}

// ---------------- MFMA flash attention: 64-k steps, dual acc chains ----------------
__global__ void __launch_bounds__(256) flash_kernel(
        const unsigned short* __restrict__ Qb, const unsigned short* __restrict__ Kb,
        const unsigned short* __restrict__ Vb,
        float* __restrict__ pl, float* __restrict__ pout) {
    const int bid = blockIdx.x;
    const int h  = bid & 3;
    const int qt = (bid >> 2) & 63;
    const int kc = bid >> 8;
    const int tid = threadIdx.x;
    const int wv = tid >> 6, lane = tid & 63;
    const int g = lane >> 4, li = lane & 15;
    const int q0 = qt * 64 + wv * 16;

    s8v qf = {0, 0, 0, 0, 0, 0, 0, 0};
    {
        s4v ql = *(const s4v*)(Qb + ((size_t)(h * P + q0 + li) << 4) + 4 * g);
        qf[0] = ql[0]; qf[1] = ql[1]; qf[2] = ql[2]; qf[3] = ql[3];
    }
    const unsigned short* Kh = Kb + ((size_t)(h * P) << 4);
    const unsigned short* Vrow = Vb + (size_t)(h * 16 + li) * P;

    f4v accA = {0.f, 0.f, 0.f, 0.f};
    f4v accB = {0.f, 0.f, 0.f, 0.f};
    float lA = 0.f, lB = 0.f;
    const int kbeg = kc * (P / KC);
    const int kend = kbeg + P / KC;
#pragma unroll 2
    for (int k0 = kbeg; k0 < kend; k0 += 64) {
        s4v t1 = *(const s4v*)(Kh + ((size_t)(k0 + li) << 4) + 4 * g);
        s4v t2 = *(const s4v*)(Kh + ((size_t)(k0 + 16 + li) << 4) + 4 * g);
        s4v t3 = *(const s4v*)(Kh + ((size_t)(k0 + 32 + li) << 4) + 4 * g);
        s4v t4 = *(const s4v*)(Kh + ((size_t)(k0 + 48 + li) << 4) + 4 * g);
        s4v v1 = *(const s4v*)(Vrow + k0 + 4 * g);
        s4v v2 = *(const s4v*)(Vrow + k0 + 16 + 4 * g);
        s4v v3 = *(const s4v*)(Vrow + k0 + 32 + 4 * g);
        s4v v4 = *(const s4v*)(Vrow + k0 + 48 + 4 * g);
        s8v ka1 = {t1[0], t1[1], t1[2], t1[3], 0, 0, 0, 0};
        s8v ka2 = {t2[0], t2[1], t2[2], t2[3], 0, 0, 0, 0};
        s8v ka3 = {t3[0], t3[1], t3[2], t3[3], 0, 0, 0, 0};
        s8v ka4 = {t4[0], t4[1], t4[2], t4[3], 0, 0, 0, 0};
        f4v z = {0.f, 0.f, 0.f, 0.f};
        f4v c1 = __builtin_amdgcn_mfma_f32_16x16x32_bf16(ka1, qf, z, 0, 0, 0);
        f4v c2 = __builtin_amdgcn_mfma_f32_16x16x32_bf16(ka2, qf, z, 0, 0, 0);
        f4v c3 = __builtin_amdgcn_mfma_f32_16x16x32_bf16(ka3, qf, z, 0, 0, 0);
        f4v c4 = __builtin_amdgcn_mfma_f32_16x16x32_bf16(ka4, qf, z, 0, 0, 0);
        float p0 = __builtin_amdgcn_exp2f(c1[0]), p1 = __builtin_amdgcn_exp2f(c1[1]);
        float p2 = __builtin_amdgcn_exp2f(c1[2]), p3 = __builtin_amdgcn_exp2f(c1[3]);
        float p4 = __builtin_amdgcn_exp2f(c2[0]), p5 = __builtin_amdgcn_exp2f(c2[1]);
        float p6 = __builtin_amdgcn_exp2f(c2[2]), p7 = __builtin_amdgcn_exp2f(c2[3]);
        float p8 = __builtin_amdgcn_exp2f(c3[0]), p9 = __builtin_amdgcn_exp2f(c3[1]);
        float pa = __builtin_amdgcn_exp2f(c3[2]), pb = __builtin_amdgcn_exp2f(c3[3]);
        float pc = __builtin_amdgcn_exp2f(c4[0]), pd = __builtin_amdgcn_exp2f(c4[1]);
        float pe = __builtin_amdgcn_exp2f(c4[2]), pf_ = __builtin_amdgcn_exp2f(c4[3]);
        lA += ((p0 + p1) + (p2 + p3)) + ((p4 + p5) + (p6 + p7));
        lB += ((p8 + p9) + (pa + pb)) + ((pc + pd) + (pe + pf_));
        s8v pf1, pf2;
        pf1[0] = (short)(__float_as_uint(p0) >> 16); pf1[1] = (short)(__float_as_uint(p1) >> 16);
        pf1[2] = (short)(__float_as_uint(p2) >> 16); pf1[3] = (short)(__float_as_uint(p3) >> 16);
        pf1[4] = (short)(__float_as_uint(p4) >> 16); pf1[5] = (short)(__float_as_uint(p5) >> 16);
        pf1[6] = (short)(__float_as_uint(p6) >> 16); pf1[7] = (short)(__float_as_uint(p7) >> 16);
        pf2[0] = (short)(__float_as_uint(p8) >> 16); pf2[1] = (short)(__float_as_uint(p9) >> 16);
        pf2[2] = (short)(__float_as_uint(pa) >> 16); pf2[3] = (short)(__float_as_uint(pb) >> 16);
        pf2[4] = (short)(__float_as_uint(pc) >> 16); pf2[5] = (short)(__float_as_uint(pd) >> 16);
        pf2[6] = (short)(__float_as_uint(pe) >> 16); pf2[7] = (short)(__float_as_uint(pf_) >> 16);
        s8v vf1 = {v1[0], v1[1], v1[2], v1[3], v2[0], v2[1], v2[2], v2[3]};
        s8v vf2 = {v3[0], v3[1], v3[2], v3[3], v4[0], v4[1], v4[2], v4[3]};
        accA = __builtin_amdgcn_mfma_f32_16x16x32_bf16(vf1, pf1, accA, 0, 0, 0);
        accB = __builtin_amdgcn_mfma_f32_16x16x32_bf16(vf2, pf2, accB, 0, 0, 0);
    }
    f4v acc = {accA[0] + accB[0], accA[1] + accB[1], accA[2] + accB[2], accA[3] + accB[3]};
    float l = lA + lB;
    l += __shfl_xor(l, 16, 64);
    l += __shfl_xor(l, 32, 64);
    const int q = q0 + li;
    const size_t gidx = (size_t)(h * P + q) * KC + kc;
    *(f4v*)(pout + gidx * 16 + 4 * g) = acc;
    if (lane < 16) pl[gidx] = l;
}

// ---------------- merge K-chunk partials -> ctx (plain sums) ----------------
__global__ void attn_merge_kernel(const float* __restrict__ pl, const float* __restrict__ pout,
                                  float* __restrict__ ctx) {
    int gt = blockIdx.x * 256 + threadIdx.x;
    int d4 = gt & 3;
    int gq = gt >> 2;
    float L = 0.f;
    f4v s = {0.f, 0.f, 0.f, 0.f};
    for (int c = 0; c < KC; ++c) {
        L += pl[(size_t)gq * KC + c];
        f4v t = *(const f4v*)(pout + ((size_t)gq * KC + c) * 16 + 4 * d4);
        s[0] += t[0]; s[1] += t[1]; s[2] += t[2]; s[3] += t[3];
    }
    float inv = 1.0f / L;
    int h = gq >> 12, q = gq & 4095;
    f4v r; r[0] = s[0] * inv; r[1] = s[1] * inv; r[2] = s[2] * inv; r[3] = s[3] * inv;
    *(f4v*)(ctx + (size_t)q * D + h * 16 + 4 * d4) = r;
}

// ---------------- output projection + MLP heads ----------------
__global__ void heads_kernel(const float* __restrict__ ctx,
                             const float* __restrict__ Wo, const float* __restrict__ bo,
                             const float* __restrict__ Wm1, const float* __restrict__ bm1,
                             const float* __restrict__ Wm2, const float* __restrict__ bm2,
                             const float* __restrict__ Wd1, const float* __restrict__ bd1,
                             const float* __restrict__ Wd2, const float* __restrict__ bd2,
                             float* __restrict__ out) {
    __shared__ float cs[4][D];
    __shared__ float x2[4][D];
    __shared__ float hid[4][D];
    const int r0 = blockIdx.x * 4;
    const int tid = threadIdx.x;
    cs[tid >> 6][tid & 63] = ctx[r0 * D + tid];
    __syncthreads();
    const int row = tid >> 6, col = tid & 63;
    float a = bo[col];
    for (int d = 0; d < D; ++d) a = fmaf(cs[row][d], Wo[d * D + col], a);
    x2[row][col] = a;
    __syncthreads();
    const int hc = col & 31;
    const float* W1 = (col < 32) ? Wm1 : Wd1;
    float hsum = (col < 32) ? bm1[hc] : bd1[hc];
    for (int d = 0; d < D; ++d) hsum = fmaf(x2[row][d], W1[d * 32 + hc], hsum);
    hsum = fmaxf(hsum, 0.0f);
    float w2 = (col < 32) ? Wm2[hc] : Wd2[hc];
    hid[row][col] = hsum * w2;
    __syncthreads();
    if (tid < 8) {
        int rr = tid >> 1, which = tid & 1;
        float s = which ? bd2[0] : bm2[0];
        for (int j2 = 0; j2 < 32; ++j2) s += hid[rr][which * 32 + j2];
        out[which * P + r0 + rr] = softplus_f(s);
    }
}

extern "C" void kernel_launch(void* const* d_in, const int* in_sizes, int n_in,
                              void* d_out, int out_size, void* d_ws, size_t ws_size,
                              hipStream_t stream) {
    const float* times = (const float*)d_in[0];
    const float* mom   = (const float*)d_in[1];
    const float* pos   = (const float*)d_in[2];
    const int*   pairs = (const int*)d_in[3];
    const float* Wenc  = (const float*)d_in[4];
    const float* benc  = (const float*)d_in[5];
    const float* pemb  = (const float*)d_in[6];
    const float* Wq = (const float*)d_in[7];   const float* bq = (const float*)d_in[8];
    const float* Wk = (const float*)d_in[9];   const float* bk = (const float*)d_in[10];
    const float* Wv = (const float*)d_in[11];  const float* bv = (const float*)d_in[12];
    const float* Wo = (const float*)d_in[13];  const float* bo = (const float*)d_in[14];
    const float* Wm1 = (const float*)d_in[15]; const float* bm1 = (const float*)d_in[16];
    const float* Wm2 = (const float*)d_in[17]; const float* bm2 = (const float*)d_in[18];
    const float* Wd1 = (const float*)d_in[19]; const float* bd1 = (const float*)d_in[20];
    const float* Wd2 = (const float*)d_in[21]; const float* bd2 = (const float*)d_in[22];

    char* wsb = (char*)d_ws;
    float4* sfeats  = (float4*)wsb;                            // P*BCAP*16 = 64 MB [reused as pout]
    int* gcount     = (int*)(wsb + (size_t)P * BCAP * 16);     // P ints
    float* x        = (float*)(gcount + P);                    // 1 MB
    unsigned short* Qb = (unsigned short*)(x + P * D);         // 512 KB
    unsigned short* Kb = Qb + (size_t)H * P * 16;              // 512 KB
    unsigned short* Vb = Kb + (size_t)H * P * 16;              // 512 KB
    float* pl       = (float*)(Vb + (size_t)H * P * 16);       // H*P*KC
    float* ctx      = pl + (size_t)H * P * KC;                 // 1 MB
    float* pout     = (float*)wsb;                             // alias sfeats (dead after gather)
    float* out      = (float*)d_out;

    hipMemsetAsync(gcount, 0, P * sizeof(int), stream);
    place_single<<<(NP + 511) / 512, 512, 0, stream>>>((const int2*)pairs, times, mom, pos,
                                                       gcount, sfeats);
    gather_kernel<<<P / 4, 512, 0, stream>>>(sfeats, gcount, Wenc, benc, pemb, x);
    qkv_kernel<<<P / 4, 256, 0, stream>>>(x, Wq, bq, Wk, bk, Wv, bv, Qb, Kb, Vb);
    flash_kernel<<<H * (P / 64) * KC, 256, 0, stream>>>(Qb, Kb, Vb, pl, pout);
    attn_merge_kernel<<<(H * P * 4) / 256, 256, 0, stream>>>(pl, pout, ctx);
    heads_kernel<<<P / 4, 256, 0, stream>>>(ctx, Wo, bo, Wm1, bm1, Wm2, bm2, Wd1, bd1, Wd2, bd2, out);
}

// Round 10
// 151.453 us; speedup vs baseline: 1.6033x; 1.6033x over previous
//
#include <hip/hip_runtime.h>
#include <math.h>

#define NP 1000000
#define NE (2 * NP)
#define P 4096
#define D 64
#define H 4
#define HD 16

#define NB 512      // blocks for hist/place passes
#define PBT 1024    // threads per pass block
#define SCB 128     // bins per scan_cols block

#define KC 8        // K-splits across blocks for flash

typedef short s4v __attribute__((ext_vector_type(4)));
typedef short s8v __attribute__((ext_vector_type(8)));
typedef float f4v __attribute__((ext_vector_type(4)));

__device__ __forceinline__ float softplus_f(float x) {
    return fmaxf(x, 0.0f) + log1pf(__expf(-fabsf(x)));
}
__device__ __forceinline__ unsigned short f2bf_rne(float f) {
    unsigned int b = __float_as_uint(f);
    b += 0x7fffu + ((b >> 16) & 1u);
    return (unsigned short)(b >> 16);
}

// ---------------- pass A: per-block bin histogram ----------------
__global__ void __launch_bounds__(PBT) hist_pass(const int* __restrict__ pairs,
                                                 int* __restrict__ hists) {
    __shared__ int lh[P];
    const int tid = threadIdx.x, blk = blockIdx.x;
    for (int i = tid; i < P; i += PBT) lh[i] = 0;
    __syncthreads();
    const int lo = (int)(((long long)blk * NE) / NB);
    const int hi = (int)(((long long)(blk + 1) * NE) / NB);
    for (int i = lo + tid; i < hi; i += PBT) atomicAdd(&lh[pairs[i]], 1);
    __syncthreads();
    for (int i = tid; i < P; i += PBT) hists[(size_t)blk * P + i] = lh[i];
}

// ---------------- column prefix over blocks: chunked LDS transpose-scan ----------------
__global__ void __launch_bounds__(1024) scan_cols(int* __restrict__ hists,
                                                  int* __restrict__ totals) {
    __shared__ int buf[64][SCB];              // 32 KB
    const int bo = blockIdx.x * SCB;          // 32 blocks x 128 bins
    const int t = threadIdx.x;
    const int col = t & (SCB - 1);
    const int row = t >> 7;                   // 0..7
    int carry = 0;                            // valid for t < SCB
    for (int c = 0; c < NB / 64; ++c) {
#pragma unroll
        for (int r8 = 0; r8 < 64; r8 += 8)
            buf[r8 + row][col] = hists[(size_t)(c * 64 + r8 + row) * P + bo + col];
        __syncthreads();
        if (t < SCB) {
            int cr = carry;
            for (int r = 0; r < 64; ++r) { int v = buf[r][t]; buf[r][t] = cr; cr += v; }
            carry = cr;
        }
        __syncthreads();
#pragma unroll
        for (int r8 = 0; r8 < 64; r8 += 8)
            hists[(size_t)(c * 64 + r8 + row) * P + bo + col] = buf[r8 + row][col];
        __syncthreads();
    }
    if (t < SCB) totals[bo + t] = carry;
}

// ---------------- exclusive scan over 4096 bins ----------------
__global__ void __launch_bounds__(1024) scan_bins(const int* __restrict__ totals,
                                                  int* __restrict__ bin_start) {
    __shared__ int sdat[1024];
    const int t = threadIdx.x;
    int a[4]; int s = 0;
#pragma unroll
    for (int k2 = 0; k2 < 4; ++k2) { a[k2] = totals[t * 4 + k2]; s += a[k2]; }
    sdat[t] = s;
    __syncthreads();
    for (int off = 1; off < 1024; off <<= 1) {
        int v = (t >= off) ? sdat[t - off] : 0;
        __syncthreads();
        sdat[t] += v;
        __syncthreads();
    }
    int run = sdat[t] - s;
#pragma unroll
    for (int k2 = 0; k2 < 4; ++k2) { bin_start[t * 4 + k2] = run; run += a[k2]; }
    if (t == 1023) bin_start[P] = run;
}

// ---------------- pass C: scatter FEATURES, 4 independent chains/thread ----------------
__global__ void __launch_bounds__(PBT) place_pass(
        const int* __restrict__ pairs, const float* __restrict__ times,
        const float* __restrict__ mom, const float* __restrict__ pos,
        const int* __restrict__ hists, const int* __restrict__ bin_start,
        float4* __restrict__ sfeats) {
    __shared__ int lc[P];
    __shared__ int loff[P];
    const int tid = threadIdx.x, blk = blockIdx.x;
    for (int i = tid; i < P; i += PBT) {
        lc[i] = 0;
        loff[i] = bin_start[i] + hists[(size_t)blk * P + i];
    }
    __syncthreads();
    const int lo = (int)(((long long)blk * NE) / NB);
    const int hi = (int)(((long long)(blk + 1) * NE) / NB);
    // entries/block <= 3907 <= 4*PBT: four predicated slots, independent chains
    int idx[4]; bool vld[4]; int bb[4]; float4 ff[4];
#pragma unroll
    for (int j = 0; j < 4; ++j) {
        idx[j] = lo + tid + j * PBT;
        vld[j] = idx[j] < hi;
        int i2 = vld[j] ? idx[j] : lo;
        int ev = i2 >> 1;
        bb[j] = pairs[i2];
        ff[j].x = times[ev]; ff[j].y = mom[ev]; ff[j].z = pos[ev]; ff[j].w = 0.0f;
    }
    int rr[4];
#pragma unroll
    for (int j = 0; j < 4; ++j)
        rr[j] = vld[j] ? atomicAdd(&lc[bb[j]], 1) : 0;
#pragma unroll
    for (int j = 0; j < 4; ++j)
        if (vld[j]) sfeats[(size_t)loff[bb[j]] + rr[j]] = ff[j];
}

// ---------------- gather-reduce: 2 waves/bin, lane = 8-entry-slot x 8-dim-group ----------------
#define GBODY(fv)                                                              \
    {                                                                          \
        float u0 = fmaf(fv.x, w0a[0], fmaf(fv.y, w1a[0], fmaf(fv.z, w2a[0], ba[0]))); \
        float u1 = fmaf(fv.x, w0a[1], fmaf(fv.y, w1a[1], fmaf(fv.z, w2a[1], ba[1]))); \
        float u2 = fmaf(fv.x, w0a[2], fmaf(fv.y, w1a[2], fmaf(fv.z, w2a[2], ba[2]))); \
        float u3 = fmaf(fv.x, w0a[3], fmaf(fv.y, w1a[3], fmaf(fv.z, w2a[3], ba[3]))); \
        float u4 = fmaf(fv.x, w0b[0], fmaf(fv.y, w1b[0], fmaf(fv.z, w2b[0], bbv[0]))); \
        float u5 = fmaf(fv.x, w0b[1], fmaf(fv.y, w1b[1], fmaf(fv.z, w2b[1], bbv[1]))); \
        float u6 = fmaf(fv.x, w0b[2], fmaf(fv.y, w1b[2], fmaf(fv.z, w2b[2], bbv[2]))); \
        float u7 = fmaf(fv.x, w0b[3], fmaf(fv.y, w1b[3], fmaf(fv.z, w2b[3], bbv[3]))); \
        racc[0] += __builtin_amdgcn_rcpf(__builtin_amdgcn_exp2f(u0) + 1.0f);   \
        racc[1] += __builtin_amdgcn_rcpf(__builtin_amdgcn_exp2f(u1) + 1.0f);   \
        racc[2] += __builtin_amdgcn_rcpf(__builtin_amdgcn_exp2f(u2) + 1.0f);   \
        racc[3] += __builtin_amdgcn_rcpf(__builtin_amdgcn_exp2f(u3) + 1.0f);   \
        racc[4] += __builtin_amdgcn_rcpf(__builtin_amdgcn_exp2f(u4) + 1.0f);   \
        racc[5] += __builtin_amdgcn_rcpf(__builtin_amdgcn_exp2f(u5) + 1.0f);   \
        racc[6] += __builtin_amdgcn_rcpf(__builtin_amdgcn_exp2f(u6) + 1.0f);   \
        racc[7] += __builtin_amdgcn_rcpf(__builtin_amdgcn_exp2f(u7) + 1.0f);   \
    }

__global__ void __launch_bounds__(512) gather_kernel(
        const float4* __restrict__ sfeats, const int* __restrict__ bin_start,
        const float* __restrict__ Wenc, const float* __restrict__ benc,
        const float* __restrict__ pemb, float* __restrict__ x) {
    __shared__ float sred[4][16][68];
    const int tid = threadIdx.x;
    const int wv = tid >> 6, ln = tid & 63;
    const int bi = wv >> 1, hw = wv & 1;
    const int es = ln & 7, dg = ln >> 3;
    const int b = blockIdx.x * 4 + bi;
    const int d0 = dg * 8;
    const float C = 2.8853900817779268f;    // 2*log2(e)
    f4v w0a = *(const f4v*)(Wenc + d0);          f4v w0b = *(const f4v*)(Wenc + d0 + 4);
    f4v w1a = *(const f4v*)(Wenc + D + d0);      f4v w1b = *(const f4v*)(Wenc + D + d0 + 4);
    f4v w2a = *(const f4v*)(Wenc + 2 * D + d0);  f4v w2b = *(const f4v*)(Wenc + 2 * D + d0 + 4);
    f4v ba  = *(const f4v*)(benc + d0);          f4v bbv = *(const f4v*)(benc + d0 + 4);
    w0a *= C; w0b *= C; w1a *= C; w1b *= C; w2a *= C; w2b *= C; ba *= C; bbv *= C;

    const int s0 = bin_start[b], s1 = bin_start[b + 1];
    const int cnt = s1 - s0;
    const int half = (cnt + 1) >> 1;
    const int lo = s0 + hw * half;
    const int hi = hw ? s1 : (s0 + half);

    float racc[8];
#pragma unroll
    for (int j = 0; j < 8; ++j) racc[j] = 0.0f;
    int ncnt = 0;
    int base = lo;
    for (; base + 16 <= hi; base += 16) {
        float4 f0 = sfeats[base + es];
        float4 f1 = sfeats[base + 8 + es];
        GBODY(f0);
        GBODY(f1);
        ncnt += 2;
    }
    if (base + 8 <= hi) {
        float4 f0 = sfeats[base + es];
        GBODY(f0);
        ncnt += 1;
        base += 8;
    }
    if (base < hi) {
        const int n = hi - base;
        const bool valid = es < n;
        float4 f = valid ? sfeats[base + es] : make_float4(0.f, 0.f, 0.f, 0.f);
        float save[8];
#pragma unroll
        for (int j = 0; j < 8; ++j) save[j] = racc[j];
        GBODY(f);
        if (!valid) {
#pragma unroll
            for (int j = 0; j < 8; ++j) racc[j] = save[j];
        } else {
            ncnt += 1;
        }
    }
    const float fn = (float)ncnt;
    float* sw = &sred[bi][hw * 8 + es][d0];
#pragma unroll
    for (int j = 0; j < 8; ++j) sw[j] = fmaf(-2.0f, racc[j], fn);
    __syncthreads();
    if (tid < 256) {
        int bin = tid >> 6, dim = tid & 63;
        float s = 0.0f;
#pragma unroll
        for (int e2 = 0; e2 < 16; ++e2) s += sred[bin][e2][dim];
        int gb = blockIdx.x * 4 + bin;
        float c2 = (float)(bin_start[gb + 1] - bin_start[gb]);
        x[gb * D + dim] = pemb[gb * D + dim] + s / fmaxf(c2, 1.0f);
    }
}

// ---------------- QKV projections -> bf16 Q (scaled by 0.25*log2e), K, V^T ----------------
__global__ void qkv_kernel(const float* __restrict__ x,
                           const float* __restrict__ Wq, const float* __restrict__ bq,
                           const float* __restrict__ Wk, const float* __restrict__ bk,
                           const float* __restrict__ Wv, const float* __restrict__ bv,
                           unsigned short* __restrict__ Qb, unsigned short* __restrict__ Kb,
                           unsigned short* __restrict__ Vb) {
    __shared__ float xs[4][D];
    const int r0 = blockIdx.x * 4;
    const int tid = threadIdx.x;
    xs[tid >> 6][tid & 63] = x[r0 * D + tid];
    __syncthreads();
    const int row = tid >> 6, col = tid & 63;
    float aq = bq[col], ak = bk[col], av = bv[col];
    for (int d = 0; d < D; ++d) {
        float xv = xs[row][d];
        aq = fmaf(xv, Wq[d * D + col], aq);
        ak = fmaf(xv, Wk[d * D + col], ak);
        av = fmaf(xv, Wv[d * D + col], av);
    }
    const int h = col >> 4, hd = col & 15, gr = r0 + row;
    Qb[((h * P + gr) << 4) + hd] = f2bf_rne(aq * 0.3606737602222409f);  // 0.25*log2(e)
    Kb[((h * P + gr) << 4) + hd] = f2bf_rne(ak);
    Vb[(size_t)(h * 16 + hd) * P + gr] = f2bf_rne(av);
}

// ---------------- MFMA flash attention: 64-k steps, dual acc chains ----------------
__global__ void __launch_bounds__(256) flash_kernel(
        const unsigned short* __restrict__ Qb, const unsigned short* __restrict__ Kb,
        const unsigned short* __restrict__ Vb,
        float* __restrict__ pl, float* __restrict__ pout) {
    const int bid = blockIdx.x;
    const int h  = bid & 3;
    const int qt = (bid >> 2) & 63;
    const int kc = bid >> 8;
    const int tid = threadIdx.x;
    const int wv = tid >> 6, lane = tid & 63;
    const int g = lane >> 4, li = lane & 15;
    const int q0 = qt * 64 + wv * 16;

    s8v qf = {0, 0, 0, 0, 0, 0, 0, 0};
    {
        s4v ql = *(const s4v*)(Qb + ((size_t)(h * P + q0 + li) << 4) + 4 * g);
        qf[0] = ql[0]; qf[1] = ql[1]; qf[2] = ql[2]; qf[3] = ql[3];
    }
    const unsigned short* Kh = Kb + ((size_t)(h * P) << 4);
    const unsigned short* Vrow = Vb + (size_t)(h * 16 + li) * P;

    f4v accA = {0.f, 0.f, 0.f, 0.f};
    f4v accB = {0.f, 0.f, 0.f, 0.f};
    float lA = 0.f, lB = 0.f;
    const int kbeg = kc * (P / KC);
    const int kend = kbeg + P / KC;
#pragma unroll 2
    for (int k0 = kbeg; k0 < kend; k0 += 64) {
        s4v t1 = *(const s4v*)(Kh + ((size_t)(k0 + li) << 4) + 4 * g);
        s4v t2 = *(const s4v*)(Kh + ((size_t)(k0 + 16 + li) << 4) + 4 * g);
        s4v t3 = *(const s4v*)(Kh + ((size_t)(k0 + 32 + li) << 4) + 4 * g);
        s4v t4 = *(const s4v*)(Kh + ((size_t)(k0 + 48 + li) << 4) + 4 * g);
        s4v v1 = *(const s4v*)(Vrow + k0 + 4 * g);
        s4v v2 = *(const s4v*)(Vrow + k0 + 16 + 4 * g);
        s4v v3 = *(const s4v*)(Vrow + k0 + 32 + 4 * g);
        s4v v4 = *(const s4v*)(Vrow + k0 + 48 + 4 * g);
        s8v ka1 = {t1[0], t1[1], t1[2], t1[3], 0, 0, 0, 0};
        s8v ka2 = {t2[0], t2[1], t2[2], t2[3], 0, 0, 0, 0};
        s8v ka3 = {t3[0], t3[1], t3[2], t3[3], 0, 0, 0, 0};
        s8v ka4 = {t4[0], t4[1], t4[2], t4[3], 0, 0, 0, 0};
        f4v z = {0.f, 0.f, 0.f, 0.f};
        f4v c1 = __builtin_amdgcn_mfma_f32_16x16x32_bf16(ka1, qf, z, 0, 0, 0);
        f4v c2 = __builtin_amdgcn_mfma_f32_16x16x32_bf16(ka2, qf, z, 0, 0, 0);
        f4v c3 = __builtin_amdgcn_mfma_f32_16x16x32_bf16(ka3, qf, z, 0, 0, 0);
        f4v c4 = __builtin_amdgcn_mfma_f32_16x16x32_bf16(ka4, qf, z, 0, 0, 0);
        float p0 = __builtin_amdgcn_exp2f(c1[0]), p1 = __builtin_amdgcn_exp2f(c1[1]);
        float p2 = __builtin_amdgcn_exp2f(c1[2]), p3 = __builtin_amdgcn_exp2f(c1[3]);
        float p4 = __builtin_amdgcn_exp2f(c2[0]), p5 = __builtin_amdgcn_exp2f(c2[1]);
        float p6 = __builtin_amdgcn_exp2f(c2[2]), p7 = __builtin_amdgcn_exp2f(c2[3]);
        float p8 = __builtin_amdgcn_exp2f(c3[0]), p9 = __builtin_amdgcn_exp2f(c3[1]);
        float pa = __builtin_amdgcn_exp2f(c3[2]), pb = __builtin_amdgcn_exp2f(c3[3]);
        float pc = __builtin_amdgcn_exp2f(c4[0]), pd = __builtin_amdgcn_exp2f(c4[1]);
        float pe = __builtin_amdgcn_exp2f(c4[2]), pf_ = __builtin_amdgcn_exp2f(c4[3]);
        lA += ((p0 + p1) + (p2 + p3)) + ((p4 + p5) + (p6 + p7));
        lB += ((p8 + p9) + (pa + pb)) + ((pc + pd) + (pe + pf_));
        s8v pf1, pf2;
        pf1[0] = (short)(__float_as_uint(p0) >> 16); pf1[1] = (short)(__float_as_uint(p1) >> 16);
        pf1[2] = (short)(__float_as_uint(p2) >> 16); pf1[3] = (short)(__float_as_uint(p3) >> 16);
        pf1[4] = (short)(__float_as_uint(p4) >> 16); pf1[5] = (short)(__float_as_uint(p5) >> 16);
        pf1[6] = (short)(__float_as_uint(p6) >> 16); pf1[7] = (short)(__float_as_uint(p7) >> 16);
        pf2[0] = (short)(__float_as_uint(p8) >> 16); pf2[1] = (short)(__float_as_uint(p9) >> 16);
        pf2[2] = (short)(__float_as_uint(pa) >> 16); pf2[3] = (short)(__float_as_uint(pb) >> 16);
        pf2[4] = (short)(__float_as_uint(pc) >> 16); pf2[5] = (short)(__float_as_uint(pd) >> 16);
        pf2[6] = (short)(__float_as_uint(pe) >> 16); pf2[7] = (short)(__float_as_uint(pf_) >> 16);
        s8v vf1 = {v1[0], v1[1], v1[2], v1[3], v2[0], v2[1], v2[2], v2[3]};
        s8v vf2 = {v3[0], v3[1], v3[2], v3[3], v4[0], v4[1], v4[2], v4[3]};
        accA = __builtin_amdgcn_mfma_f32_16x16x32_bf16(vf1, pf1, accA, 0, 0, 0);
        accB = __builtin_amdgcn_mfma_f32_16x16x32_bf16(vf2, pf2, accB, 0, 0, 0);
    }
    f4v acc = {accA[0] + accB[0], accA[1] + accB[1], accA[2] + accB[2], accA[3] + accB[3]};
    float l = lA + lB;
    l += __shfl_xor(l, 16, 64);
    l += __shfl_xor(l, 32, 64);
    const int q = q0 + li;
    const size_t gidx = (size_t)(h * P + q) * KC + kc;
    *(f4v*)(pout + gidx * 16 + 4 * g) = acc;
    if (lane < 16) pl[gidx] = l;
}

// ---------------- merge K-chunk partials -> ctx (plain sums) ----------------
__global__ void attn_merge_kernel(const float* __restrict__ pl, const float* __restrict__ pout,
                                  float* __restrict__ ctx) {
    int gt = blockIdx.x * 256 + threadIdx.x;
    int d4 = gt & 3;
    int gq = gt >> 2;
    float L = 0.f;
    f4v s = {0.f, 0.f, 0.f, 0.f};
    for (int c = 0; c < KC; ++c) {
        L += pl[(size_t)gq * KC + c];
        f4v t = *(const f4v*)(pout + ((size_t)gq * KC + c) * 16 + 4 * d4);
        s[0] += t[0]; s[1] += t[1]; s[2] += t[2]; s[3] += t[3];
    }
    float inv = 1.0f / L;
    int h = gq >> 12, q = gq & 4095;
    f4v r; r[0] = s[0] * inv; r[1] = s[1] * inv; r[2] = s[2] * inv; r[3] = s[3] * inv;
    *(f4v*)(ctx + (size_t)q * D + h * 16 + 4 * d4) = r;
}

// ---------------- output projection + MLP heads ----------------
__global__ void heads_kernel(const float* __restrict__ ctx,
                             const float* __restrict__ Wo, const float* __restrict__ bo,
                             const float* __restrict__ Wm1, const float* __restrict__ bm1,
                             const float* __restrict__ Wm2, const float* __restrict__ bm2,
                             const float* __restrict__ Wd1, const float* __restrict__ bd1,
                             const float* __restrict__ Wd2, const float* __restrict__ bd2,
                             float* __restrict__ out) {
    __shared__ float cs[4][D];
    __shared__ float x2[4][D];
    __shared__ float hid[4][D];
    const int r0 = blockIdx.x * 4;
    const int tid = threadIdx.x;
    cs[tid >> 6][tid & 63] = ctx[r0 * D + tid];
    __syncthreads();
    const int row = tid >> 6, col = tid & 63;
    float a = bo[col];
    for (int d = 0; d < D; ++d) a = fmaf(cs[row][d], Wo[d * D + col], a);
    x2[row][col] = a;
    __syncthreads();
    const int hc = col & 31;
    const float* W1 = (col < 32) ? Wm1 : Wd1;
    float hsum = (col < 32) ? bm1[hc] : bd1[hc];
    for (int d = 0; d < D; ++d) hsum = fmaf(x2[row][d], W1[d * 32 + hc], hsum);
    hsum = fmaxf(hsum, 0.0f);
    float w2 = (col < 32) ? Wm2[hc] : Wd2[hc];
    hid[row][col] = hsum * w2;
    __syncthreads();
    if (tid < 8) {
        int rr = tid >> 1, which = tid & 1;
        float s = which ? bd2[0] : bm2[0];
        for (int j2 = 0; j2 < 32; ++j2) s += hid[rr][which * 32 + j2];
        out[which * P + r0 + rr] = softplus_f(s);
    }
}

extern "C" void kernel_launch(void* const* d_in, const int* in_sizes, int n_in,
                              void* d_out, int out_size, void* d_ws, size_t ws_size,
                              hipStream_t stream) {
    const float* times = (const float*)d_in[0];
    const float* mom   = (const float*)d_in[1];
    const float* pos   = (const float*)d_in[2];
    const int*   pairs = (const int*)d_in[3];
    const float* Wenc  = (const float*)d_in[4];
    const float* benc  = (const float*)d_in[5];
    const float* pemb  = (const float*)d_in[6];
    const float* Wq = (const float*)d_in[7];   const float* bq = (const float*)d_in[8];
    const float* Wk = (const float*)d_in[9];   const float* bk = (const float*)d_in[10];
    const float* Wv = (const float*)d_in[11];  const float* bv = (const float*)d_in[12];
    const float* Wo = (const float*)d_in[13];  const float* bo = (const float*)d_in[14];
    const float* Wm1 = (const float*)d_in[15]; const float* bm1 = (const float*)d_in[16];
    const float* Wm2 = (const float*)d_in[17]; const float* bm2 = (const float*)d_in[18];
    const float* Wd1 = (const float*)d_in[19]; const float* bd1 = (const float*)d_in[20];
    const float* Wd2 = (const float*)d_in[21]; const float* bd2 = (const float*)d_in[22];

    char* wsb = (char*)d_ws;
    float4* sfeats  = (float4*)wsb;                            // NE*16 = 32 MB [reused as pout]
    int* hists      = (int*)(wsb + (size_t)NE * 16);           // NB*P = 8 MB
    int* totals     = hists + (size_t)NB * P;
    int* bin_start  = totals + P;
    float* x        = (float*)(bin_start + P + 2);             // 1 MB
    unsigned short* Qb = (unsigned short*)(x + P * D);         // 512 KB
    unsigned short* Kb = Qb + (size_t)H * P * 16;              // 512 KB
    unsigned short* Vb = Kb + (size_t)H * P * 16;              // 512 KB
    float* pl       = (float*)(Vb + (size_t)H * P * 16);       // H*P*KC
    float* ctx      = pl + (size_t)H * P * KC;                 // 1 MB
    float* pout     = (float*)wsb;                             // alias sfeats (dead after gather)
    float* out      = (float*)d_out;

    hist_pass<<<NB, PBT, 0, stream>>>(pairs, hists);
    scan_cols<<<P / SCB, 1024, 0, stream>>>(hists, totals);
    scan_bins<<<1, 1024, 0, stream>>>(totals, bin_start);
    place_pass<<<NB, PBT, 0, stream>>>(pairs, times, mom, pos, hists, bin_start, sfeats);
    gather_kernel<<<P / 4, 512, 0, stream>>>(sfeats, bin_start, Wenc, benc, pemb, x);
    qkv_kernel<<<P / 4, 256, 0, stream>>>(x, Wq, bq, Wk, bk, Wv, bv, Qb, Kb, Vb);
    flash_kernel<<<H * (P / 64) * KC, 256, 0, stream>>>(Qb, Kb, Vb, pl, pout);
    attn_merge_kernel<<<(H * P * 4) / 256, 256, 0, stream>>>(pl, pout, ctx);
    heads_kernel<<<P / 4, 256, 0, stream>>>(ctx, Wo, bo, Wm1, bm1, Wm2, bm2, Wd1, bd1, Wd2, bd2, out);
}

// Round 11
// 126.196 us; speedup vs baseline: 1.9241x; 1.2001x over previous
//
#include <hip/hip_runtime.h>
#include <math.h>

#define NP 1000000
#define NE (2 * NP)
#define P 4096
#define D 64
#define H 4
#define HD 16

#define NB 512      // blocks for hist/place passes
#define PBT 1024    // threads per pass block
#define SCB 128     // bins per scan_cols block

#define KC 8        // K-splits across blocks for flash

typedef short s4v __attribute__((ext_vector_type(4)));
typedef short s8v __attribute__((ext_vector_type(8)));
typedef float f4v __attribute__((ext_vector_type(4)));

__device__ __forceinline__ float softplus_f(float x) {
    return fmaxf(x, 0.0f) + log1pf(__expf(-fabsf(x)));
}
__device__ __forceinline__ unsigned short f2bf_rne(float f) {
    unsigned int b = __float_as_uint(f);
    b += 0x7fffu + ((b >> 16) & 1u);
    return (unsigned short)(b >> 16);
}

// ---------------- pass A: per-block bin histogram ----------------
__global__ void __launch_bounds__(PBT) hist_pass(const int* __restrict__ pairs,
                                                 int* __restrict__ hists) {
    __shared__ int lh[P];
    const int tid = threadIdx.x, blk = blockIdx.x;
    for (int i = tid; i < P; i += PBT) lh[i] = 0;
    __syncthreads();
    const int lo = (int)(((long long)blk * NE) / NB);
    const int hi = (int)(((long long)(blk + 1) * NE) / NB);
    for (int i = lo + tid; i < hi; i += PBT) atomicAdd(&lh[pairs[i]], 1);
    __syncthreads();
    for (int i = tid; i < P; i += PBT) hists[(size_t)blk * P + i] = lh[i];
}

// ---------------- column prefix over blocks: chunked LDS transpose-scan ----------------
__global__ void __launch_bounds__(1024) scan_cols(int* __restrict__ hists,
                                                  int* __restrict__ totals) {
    __shared__ int buf[64][SCB];              // 32 KB
    const int bo = blockIdx.x * SCB;
    const int t = threadIdx.x;
    const int col = t & (SCB - 1);
    const int row = t >> 7;                   // 0..7
    int carry = 0;                            // valid for t < SCB
    for (int c = 0; c < NB / 64; ++c) {
#pragma unroll
        for (int r8 = 0; r8 < 64; r8 += 8)
            buf[r8 + row][col] = hists[(size_t)(c * 64 + r8 + row) * P + bo + col];
        __syncthreads();
        if (t < SCB) {
            int cr = carry;
            for (int r = 0; r < 64; ++r) { int v = buf[r][t]; buf[r][t] = cr; cr += v; }
            carry = cr;
        }
        __syncthreads();
#pragma unroll
        for (int r8 = 0; r8 < 64; r8 += 8)
            hists[(size_t)(c * 64 + r8 + row) * P + bo + col] = buf[r8 + row][col];
        __syncthreads();
    }
    if (t < SCB) totals[bo + t] = carry;
}

// ---------------- exclusive scan over 4096 bins ----------------
__global__ void __launch_bounds__(1024) scan_bins(const int* __restrict__ totals,
                                                  int* __restrict__ bin_start) {
    __shared__ int sdat[1024];
    const int t = threadIdx.x;
    int a[4]; int s = 0;
#pragma unroll
    for (int k2 = 0; k2 < 4; ++k2) { a[k2] = totals[t * 4 + k2]; s += a[k2]; }
    sdat[t] = s;
    __syncthreads();
    for (int off = 1; off < 1024; off <<= 1) {
        int v = (t >= off) ? sdat[t - off] : 0;
        __syncthreads();
        sdat[t] += v;
        __syncthreads();
    }
    int run = sdat[t] - s;
#pragma unroll
    for (int k2 = 0; k2 < 4; ++k2) { bin_start[t * 4 + k2] = run; run += a[k2]; }
    if (t == 1023) bin_start[P] = run;
}

// ---------------- pass C: scatter FEATURES, 4 independent chains/thread ----------------
__global__ void __launch_bounds__(PBT) place_pass(
        const int* __restrict__ pairs, const float* __restrict__ times,
        const float* __restrict__ mom, const float* __restrict__ pos,
        const int* __restrict__ hists, const int* __restrict__ bin_start,
        float4* __restrict__ sfeats) {
    __shared__ int lc[P];
    __shared__ int loff[P];
    const int tid = threadIdx.x, blk = blockIdx.x;
    for (int i = tid; i < P; i += PBT) {
        lc[i] = 0;
        loff[i] = bin_start[i] + hists[(size_t)blk * P + i];
    }
    __syncthreads();
    const int lo = (int)(((long long)blk * NE) / NB);
    const int hi = (int)(((long long)(blk + 1) * NE) / NB);
    int idx[4]; bool vld[4]; int bb[4]; float4 ff[4];
#pragma unroll
    for (int j = 0; j < 4; ++j) {
        idx[j] = lo + tid + j * PBT;
        vld[j] = idx[j] < hi;
        int i2 = vld[j] ? idx[j] : lo;
        int ev = i2 >> 1;
        bb[j] = pairs[i2];
        ff[j].x = times[ev]; ff[j].y = mom[ev]; ff[j].z = pos[ev]; ff[j].w = 0.0f;
    }
    int rr[4];
#pragma unroll
    for (int j = 0; j < 4; ++j)
        rr[j] = vld[j] ? atomicAdd(&lc[bb[j]], 1) : 0;
#pragma unroll
    for (int j = 0; j < 4; ++j)
        if (vld[j]) sfeats[(size_t)loff[bb[j]] + rr[j]] = ff[j];
}

// ---------------- gather-reduce: 2 waves/bin, lane = 8-entry-slot x 8-dim-group ----------------
#define GBODY(fv)                                                              \
    {                                                                          \
        float u0 = fmaf(fv.x, w0a[0], fmaf(fv.y, w1a[0], fmaf(fv.z, w2a[0], ba[0]))); \
        float u1 = fmaf(fv.x, w0a[1], fmaf(fv.y, w1a[1], fmaf(fv.z, w2a[1], ba[1]))); \
        float u2 = fmaf(fv.x, w0a[2], fmaf(fv.y, w1a[2], fmaf(fv.z, w2a[2], ba[2]))); \
        float u3 = fmaf(fv.x, w0a[3], fmaf(fv.y, w1a[3], fmaf(fv.z, w2a[3], ba[3]))); \
        float u4 = fmaf(fv.x, w0b[0], fmaf(fv.y, w1b[0], fmaf(fv.z, w2b[0], bbv[0]))); \
        float u5 = fmaf(fv.x, w0b[1], fmaf(fv.y, w1b[1], fmaf(fv.z, w2b[1], bbv[1]))); \
        float u6 = fmaf(fv.x, w0b[2], fmaf(fv.y, w1b[2], fmaf(fv.z, w2b[2], bbv[2]))); \
        float u7 = fmaf(fv.x, w0b[3], fmaf(fv.y, w1b[3], fmaf(fv.z, w2b[3], bbv[3]))); \
        racc[0] += __builtin_amdgcn_rcpf(__builtin_amdgcn_exp2f(u0) + 1.0f);   \
        racc[1] += __builtin_amdgcn_rcpf(__builtin_amdgcn_exp2f(u1) + 1.0f);   \
        racc[2] += __builtin_amdgcn_rcpf(__builtin_amdgcn_exp2f(u2) + 1.0f);   \
        racc[3] += __builtin_amdgcn_rcpf(__builtin_amdgcn_exp2f(u3) + 1.0f);   \
        racc[4] += __builtin_amdgcn_rcpf(__builtin_amdgcn_exp2f(u4) + 1.0f);   \
        racc[5] += __builtin_amdgcn_rcpf(__builtin_amdgcn_exp2f(u5) + 1.0f);   \
        racc[6] += __builtin_amdgcn_rcpf(__builtin_amdgcn_exp2f(u6) + 1.0f);   \
        racc[7] += __builtin_amdgcn_rcpf(__builtin_amdgcn_exp2f(u7) + 1.0f);   \
    }

__global__ void __launch_bounds__(512) gather_kernel(
        const float4* __restrict__ sfeats, const int* __restrict__ bin_start,
        const float* __restrict__ Wenc, const float* __restrict__ benc,
        const float* __restrict__ pemb, float* __restrict__ x) {
    __shared__ float sred[4][16][68];
    const int tid = threadIdx.x;
    const int wv = tid >> 6, ln = tid & 63;
    const int bi = wv >> 1, hw = wv & 1;
    const int es = ln & 7, dg = ln >> 3;
    const int b = blockIdx.x * 4 + bi;
    const int d0 = dg * 8;
    const float C = 2.8853900817779268f;    // 2*log2(e)
    f4v w0a = *(const f4v*)(Wenc + d0);          f4v w0b = *(const f4v*)(Wenc + d0 + 4);
    f4v w1a = *(const f4v*)(Wenc + D + d0);      f4v w1b = *(const f4v*)(Wenc + D + d0 + 4);
    f4v w2a = *(const f4v*)(Wenc + 2 * D + d0);  f4v w2b = *(const f4v*)(Wenc + 2 * D + d0 + 4);
    f4v ba  = *(const f4v*)(benc + d0);          f4v bbv = *(const f4v*)(benc + d0 + 4);
    w0a *= C; w0b *= C; w1a *= C; w1b *= C; w2a *= C; w2b *= C; ba *= C; bbv *= C;

    const int s0 = bin_start[b], s1 = bin_start[b + 1];
    const int cnt = s1 - s0;
    const int half = (cnt + 1) >> 1;
    const int lo = s0 + hw * half;
    const int hi = hw ? s1 : (s0 + half);

    float racc[8];
#pragma unroll
    for (int j = 0; j < 8; ++j) racc[j] = 0.0f;
    int ncnt = 0;
    int base = lo;
    for (; base + 16 <= hi; base += 16) {
        float4 f0 = sfeats[base + es];
        float4 f1 = sfeats[base + 8 + es];
        GBODY(f0);
        GBODY(f1);
        ncnt += 2;
    }
    if (base + 8 <= hi) {
        float4 f0 = sfeats[base + es];
        GBODY(f0);
        ncnt += 1;
        base += 8;
    }
    if (base < hi) {
        const int n = hi - base;
        const bool valid = es < n;
        float4 f = valid ? sfeats[base + es] : make_float4(0.f, 0.f, 0.f, 0.f);
        float save[8];
#pragma unroll
        for (int j = 0; j < 8; ++j) save[j] = racc[j];
        GBODY(f);
        if (!valid) {
#pragma unroll
            for (int j = 0; j < 8; ++j) racc[j] = save[j];
        } else {
            ncnt += 1;
        }
    }
    const float fn = (float)ncnt;
    float* sw = &sred[bi][hw * 8 + es][d0];
#pragma unroll
    for (int j = 0; j < 8; ++j) sw[j] = fmaf(-2.0f, racc[j], fn);
    __syncthreads();
    if (tid < 256) {
        int bin = tid >> 6, dim = tid & 63;
        float s = 0.0f;
#pragma unroll
        for (int e2 = 0; e2 < 16; ++e2) s += sred[bin][e2][dim];
        int gb = blockIdx.x * 4 + bin;
        float c2 = (float)(bin_start[gb + 1] - bin_start[gb]);
        x[gb * D + dim] = pemb[gb * D + dim] + s / fmaxf(c2, 1.0f);
    }
}

// ---------------- QKV -> bf16 Q (row frag layout), K/V (fragment-linear) ----------------
// Kf/Vf layout: [h][kb=k/32][lane=g*16+li][e=0..7] -- exactly the 8 bf16 each flash
// lane consumes per 32-k block, so flash loads are single coalesced dwordx4.
__global__ void qkv_kernel(const float* __restrict__ x,
                           const float* __restrict__ Wq, const float* __restrict__ bq,
                           const float* __restrict__ Wk, const float* __restrict__ bk,
                           const float* __restrict__ Wv, const float* __restrict__ bv,
                           unsigned short* __restrict__ Qb, unsigned short* __restrict__ Kf,
                           unsigned short* __restrict__ Vf) {
    __shared__ float xs[4][D];
    const int r0 = blockIdx.x * 4;
    const int tid = threadIdx.x;
    xs[tid >> 6][tid & 63] = x[r0 * D + tid];
    __syncthreads();
    const int row = tid >> 6, col = tid & 63;
    float aq = bq[col], ak = bk[col], av = bv[col];
    for (int d = 0; d < D; ++d) {
        float xv = xs[row][d];
        aq = fmaf(xv, Wq[d * D + col], aq);
        ak = fmaf(xv, Wk[d * D + col], ak);
        av = fmaf(xv, Wv[d * D + col], av);
    }
    const int h = col >> 4, hd = col & 15, gr = r0 + row;
    Qb[((h * P + gr) << 4) + hd] = f2bf_rne(aq * 0.3606737602222409f);  // 0.25*log2(e)
    const int kb = gr >> 5, kk = gr & 31, up = kk >> 4;
    // K fragment: lane (g=hd>>2, li=kk&15), elem = up*4 + (hd&3)
    Kf[(((size_t)h * 128 + kb) * 64 + (hd >> 2) * 16 + (kk & 15)) * 8 + up * 4 + (hd & 3)] =
        f2bf_rne(ak);
    // V fragment: lane (g=(kk&15)>>2, li=hd), elem = up*4 + (kk&3)
    Vf[(((size_t)h * 128 + kb) * 64 + ((kk & 15) >> 2) * 16 + hd) * 8 + up * 4 + (kk & 3)] =
        f2bf_rne(av);
}

// ---------------- MFMA flash attention: fragment-linear operands, dual acc ----------------
__global__ void __launch_bounds__(256) flash_kernel(
        const unsigned short* __restrict__ Qb, const unsigned short* __restrict__ Kf,
        const unsigned short* __restrict__ Vf,
        float* __restrict__ pl, float* __restrict__ pout) {
    const int bid = blockIdx.x;
    const int h  = bid & 3;
    const int qt = (bid >> 2) & 63;
    const int kc = bid >> 8;
    const int tid = threadIdx.x;
    const int wv = tid >> 6, lane = tid & 63;
    const int g = lane >> 4, li = lane & 15;
    const int q0 = qt * 64 + wv * 16;

    s8v qf = {0, 0, 0, 0, 0, 0, 0, 0};
    {
        s4v ql = *(const s4v*)(Qb + ((size_t)(h * P + q0 + li) << 4) + 4 * g);
        qf[0] = ql[0]; qf[1] = ql[1]; qf[2] = ql[2]; qf[3] = ql[3];
    }
    const unsigned short* Kh = Kf + (size_t)h * 128 * 512;   // 64 lanes * 8
    const unsigned short* Vh = Vf + (size_t)h * 128 * 512;

    f4v accA = {0.f, 0.f, 0.f, 0.f};
    f4v accB = {0.f, 0.f, 0.f, 0.f};
    float lA = 0.f, lB = 0.f;
    const int kb0 = kc * (P / KC / 32);
    const int kb1 = kb0 + P / KC / 32;
#pragma unroll 4
    for (int kb = kb0; kb < kb1; kb += 2) {
        s8v kf1 = *(const s8v*)(Kh + ((size_t)kb * 64 + lane) * 8);
        s8v kf2 = *(const s8v*)(Kh + ((size_t)(kb + 1) * 64 + lane) * 8);
        s8v vf1 = *(const s8v*)(Vh + ((size_t)kb * 64 + lane) * 8);
        s8v vf2 = *(const s8v*)(Vh + ((size_t)(kb + 1) * 64 + lane) * 8);
        s8v ka1 = {kf1[0], kf1[1], kf1[2], kf1[3], 0, 0, 0, 0};
        s8v ka2 = {kf1[4], kf1[5], kf1[6], kf1[7], 0, 0, 0, 0};
        s8v ka3 = {kf2[0], kf2[1], kf2[2], kf2[3], 0, 0, 0, 0};
        s8v ka4 = {kf2[4], kf2[5], kf2[6], kf2[7], 0, 0, 0, 0};
        f4v z = {0.f, 0.f, 0.f, 0.f};
        f4v c1 = __builtin_amdgcn_mfma_f32_16x16x32_bf16(ka1, qf, z, 0, 0, 0);
        f4v c2 = __builtin_amdgcn_mfma_f32_16x16x32_bf16(ka2, qf, z, 0, 0, 0);
        f4v c3 = __builtin_amdgcn_mfma_f32_16x16x32_bf16(ka3, qf, z, 0, 0, 0);
        f4v c4 = __builtin_amdgcn_mfma_f32_16x16x32_bf16(ka4, qf, z, 0, 0, 0);
        float p0 = __builtin_amdgcn_exp2f(c1[0]), p1 = __builtin_amdgcn_exp2f(c1[1]);
        float p2 = __builtin_amdgcn_exp2f(c1[2]), p3 = __builtin_amdgcn_exp2f(c1[3]);
        float p4 = __builtin_amdgcn_exp2f(c2[0]), p5 = __builtin_amdgcn_exp2f(c2[1]);
        float p6 = __builtin_amdgcn_exp2f(c2[2]), p7 = __builtin_amdgcn_exp2f(c2[3]);
        float p8 = __builtin_amdgcn_exp2f(c3[0]), p9 = __builtin_amdgcn_exp2f(c3[1]);
        float pa = __builtin_amdgcn_exp2f(c3[2]), pb = __builtin_amdgcn_exp2f(c3[3]);
        float pc = __builtin_amdgcn_exp2f(c4[0]), pd = __builtin_amdgcn_exp2f(c4[1]);
        float pe = __builtin_amdgcn_exp2f(c4[2]), pf_ = __builtin_amdgcn_exp2f(c4[3]);
        lA += ((p0 + p1) + (p2 + p3)) + ((p4 + p5) + (p6 + p7));
        lB += ((p8 + p9) + (pa + pb)) + ((pc + pd) + (pe + pf_));
        s8v pf1, pf2;
        pf1[0] = (short)(__float_as_uint(p0) >> 16); pf1[1] = (short)(__float_as_uint(p1) >> 16);
        pf1[2] = (short)(__float_as_uint(p2) >> 16); pf1[3] = (short)(__float_as_uint(p3) >> 16);
        pf1[4] = (short)(__float_as_uint(p4) >> 16); pf1[5] = (short)(__float_as_uint(p5) >> 16);
        pf1[6] = (short)(__float_as_uint(p6) >> 16); pf1[7] = (short)(__float_as_uint(p7) >> 16);
        pf2[0] = (short)(__float_as_uint(p8) >> 16); pf2[1] = (short)(__float_as_uint(p9) >> 16);
        pf2[2] = (short)(__float_as_uint(pa) >> 16); pf2[3] = (short)(__float_as_uint(pb) >> 16);
        pf2[4] = (short)(__float_as_uint(pc) >> 16); pf2[5] = (short)(__float_as_uint(pd) >> 16);
        pf2[6] = (short)(__float_as_uint(pe) >> 16); pf2[7] = (short)(__float_as_uint(pf_) >> 16);
        accA = __builtin_amdgcn_mfma_f32_16x16x32_bf16(vf1, pf1, accA, 0, 0, 0);
        accB = __builtin_amdgcn_mfma_f32_16x16x32_bf16(vf2, pf2, accB, 0, 0, 0);
    }
    f4v acc = {accA[0] + accB[0], accA[1] + accB[1], accA[2] + accB[2], accA[3] + accB[3]};
    float l = lA + lB;
    l += __shfl_xor(l, 16, 64);
    l += __shfl_xor(l, 32, 64);
    const int q = q0 + li;
    const size_t gidx = (size_t)(h * P + q) * KC + kc;
    *(f4v*)(pout + gidx * 16 + 4 * g) = acc;
    if (lane < 16) pl[gidx] = l;
}

// ---------------- merge K-chunk partials -> ctx (plain sums) ----------------
__global__ void attn_merge_kernel(const float* __restrict__ pl, const float* __restrict__ pout,
                                  float* __restrict__ ctx) {
    int gt = blockIdx.x * 256 + threadIdx.x;
    int d4 = gt & 3;
    int gq = gt >> 2;
    float L = 0.f;
    f4v s = {0.f, 0.f, 0.f, 0.f};
    for (int c = 0; c < KC; ++c) {
        L += pl[(size_t)gq * KC + c];
        f4v t = *(const f4v*)(pout + ((size_t)gq * KC + c) * 16 + 4 * d4);
        s[0] += t[0]; s[1] += t[1]; s[2] += t[2]; s[3] += t[3];
    }
    float inv = 1.0f / L;
    int h = gq >> 12, q = gq & 4095;
    f4v r; r[0] = s[0] * inv; r[1] = s[1] * inv; r[2] = s[2] * inv; r[3] = s[3] * inv;
    *(f4v*)(ctx + (size_t)q * D + h * 16 + 4 * d4) = r;
}

// ---------------- output projection + MLP heads ----------------
__global__ void heads_kernel(const float* __restrict__ ctx,
                             const float* __restrict__ Wo, const float* __restrict__ bo,
                             const float* __restrict__ Wm1, const float* __restrict__ bm1,
                             const float* __restrict__ Wm2, const float* __restrict__ bm2,
                             const float* __restrict__ Wd1, const float* __restrict__ bd1,
                             const float* __restrict__ Wd2, const float* __restrict__ bd2,
                             float* __restrict__ out) {
    __shared__ float cs[4][D];
    __shared__ float x2[4][D];
    __shared__ float hid[4][D];
    const int r0 = blockIdx.x * 4;
    const int tid = threadIdx.x;
    cs[tid >> 6][tid & 63] = ctx[r0 * D + tid];
    __syncthreads();
    const int row = tid >> 6, col = tid & 63;
    float a = bo[col];
    for (int d = 0; d < D; ++d) a = fmaf(cs[row][d], Wo[d * D + col], a);
    x2[row][col] = a;
    __syncthreads();
    const int hc = col & 31;
    const float* W1 = (col < 32) ? Wm1 : Wd1;
    float hsum = (col < 32) ? bm1[hc] : bd1[hc];
    for (int d = 0; d < D; ++d) hsum = fmaf(x2[row][d], W1[d * 32 + hc], hsum);
    hsum = fmaxf(hsum, 0.0f);
    float w2 = (col < 32) ? Wm2[hc] : Wd2[hc];
    hid[row][col] = hsum * w2;
    __syncthreads();
    if (tid < 8) {
        int rr = tid >> 1, which = tid & 1;
        float s = which ? bd2[0] : bm2[0];
        for (int j2 = 0; j2 < 32; ++j2) s += hid[rr][which * 32 + j2];
        out[which * P + r0 + rr] = softplus_f(s);
    }
}

extern "C" void kernel_launch(void* const* d_in, const int* in_sizes, int n_in,
                              void* d_out, int out_size, void* d_ws, size_t ws_size,
                              hipStream_t stream) {
    const float* times = (const float*)d_in[0];
    const float* mom   = (const float*)d_in[1];
    const float* pos   = (const float*)d_in[2];
    const int*   pairs = (const int*)d_in[3];
    const float* Wenc  = (const float*)d_in[4];
    const float* benc  = (const float*)d_in[5];
    const float* pemb  = (const float*)d_in[6];
    const float* Wq = (const float*)d_in[7];   const float* bq = (const float*)d_in[8];
    const float* Wk = (const float*)d_in[9];   const float* bk = (const float*)d_in[10];
    const float* Wv = (const float*)d_in[11];  const float* bv = (const float*)d_in[12];
    const float* Wo = (const float*)d_in[13];  const float* bo = (const float*)d_in[14];
    const float* Wm1 = (const float*)d_in[15]; const float* bm1 = (const float*)d_in[16];
    const float* Wm2 = (const float*)d_in[17]; const float* bm2 = (const float*)d_in[18];
    const float* Wd1 = (const float*)d_in[19]; const float* bd1 = (const float*)d_in[20];
    const float* Wd2 = (const float*)d_in[21]; const float* bd2 = (const float*)d_in[22];

    char* wsb = (char*)d_ws;
    float4* sfeats  = (float4*)wsb;                            // NE*16 = 32 MB [reused as pout]
    int* hists      = (int*)(wsb + (size_t)NE * 16);           // NB*P = 8 MB
    int* totals     = hists + (size_t)NB * P;
    int* bin_start  = totals + P;
    float* x        = (float*)(bin_start + P + 2);             // 1 MB
    unsigned short* Qb = (unsigned short*)(x + P * D);         // 512 KB
    unsigned short* Kf = Qb + (size_t)H * P * 16;              // 512 KB
    unsigned short* Vf = Kf + (size_t)H * P * 16;              // 512 KB
    float* pl       = (float*)(Vf + (size_t)H * P * 16);       // H*P*KC
    float* ctx      = pl + (size_t)H * P * KC;                 // 1 MB
    float* pout     = (float*)wsb;                             // alias sfeats (dead after gather)
    float* out      = (float*)d_out;

    hist_pass<<<NB, PBT, 0, stream>>>(pairs, hists);
    scan_cols<<<P / SCB, 1024, 0, stream>>>(hists, totals);
    scan_bins<<<1, 1024, 0, stream>>>(totals, bin_start);
    place_pass<<<NB, PBT, 0, stream>>>(pairs, times, mom, pos, hists, bin_start, sfeats);
    gather_kernel<<<P / 4, 512, 0, stream>>>(sfeats, bin_start, Wenc, benc, pemb, x);
    qkv_kernel<<<P / 4, 256, 0, stream>>>(x, Wq, bq, Wk, bk, Wv, bv, Qb, Kf, Vf);
    flash_kernel<<<H * (P / 64) * KC, 256, 0, stream>>>(Qb, Kf, Vf, pl, pout);
    attn_merge_kernel<<<(H * P * 4) / 256, 256, 0, stream>>>(pl, pout, ctx);
    heads_kernel<<<P / 4, 256, 0, stream>>>(ctx, Wo, bo, Wm1, bm1, Wm2, bm2, Wd1, bd1, Wd2, bd2, out);
}